// Round 4
// baseline (572.809 us; speedup 1.0000x reference)
//
#include <hip/hip_runtime.h>

typedef unsigned int uint;
typedef unsigned short ushort_t;
typedef unsigned long long u64;
typedef __attribute__((ext_vector_type(4))) float f32x4;
typedef __attribute__((ext_vector_type(8))) __bf16 bf16x8;
typedef __attribute__((ext_vector_type(8))) unsigned short us8;

#define BATCH 65536
#define VEC 512
#define K 1024
#define GAMMA 0.99f
#define EPS 1e-05f

#define BM 128
#define BN 128
#define BK 32
#define NK (VEC / BK)   // 16
#define SEG 64

__device__ __forceinline__ ushort_t hi_of(float f) {
    return (ushort_t)(__float_as_uint(f) >> 16);
}
__device__ __forceinline__ ushort_t lo_of(float f) {
    float fhi = __uint_as_float(__float_as_uint(f) & 0xffff0000u);
    return (ushort_t)(__float_as_uint(f - fhi) >> 16);
}

__device__ __forceinline__ void gl16(const void* g, void* l) {
    __builtin_amdgcn_global_load_lds(
        (const __attribute__((address_space(1))) unsigned int*)g,
        (__attribute__((address_space(3))) unsigned int*)l, 16, 0, 0);
}

// ---- column norms of weight (VEC,K) ----
__global__ void k_w2(const float* __restrict__ w, float* __restrict__ w2) {
    __shared__ float red[16][17];
    const int c = blockIdx.x * 16 + (threadIdx.x & 15);
    const int vg = threadIdx.x >> 4;
    float s = 0.f;
    for (int i = 0; i < 32; ++i) {
        float t = w[(size_t)(vg * 32 + i) * K + c];
        s += t * t;
    }
    red[vg][threadIdx.x & 15] = s;
    __syncthreads();
    if (vg == 0) {
        float acc = 0.f;
#pragma unroll
        for (int g = 0; g < 16; ++g) acc += red[g][threadIdx.x & 15];
        w2[c] = acc;
    }
}

// ---- pack w into B-fragment granules: [gx*16+ks][ct 8][half 2][lane 64] us8 ----
__global__ void k_pack_w(const float* __restrict__ w, us8* __restrict__ wpk) {
    const int g = blockIdx.x;            // gx*16 + ks
    const int gx = g >> 4, ks = g & 15;
    const int t = threadIdx.x;
    us8* dst = wpk + (size_t)g * 1024;
#pragma unroll
    for (int i = 0; i < 4; ++i) {
        const int o = i * 256 + t;
        const int lane = o & 63, half = (o >> 6) & 1, ct = o >> 7;
        const int col = gx * 128 + ct * 16 + (lane & 15);
        const int kb = ks * 32 + (lane >> 4) * 8;
        us8 v;
#pragma unroll
        for (int j = 0; j < 8; ++j) {
            float f = w[(size_t)(kb + j) * K + col];
            v[j] = half ? lo_of(f) : hi_of(f);
        }
        dst[o] = v;
    }
}

// ---- pack x into A-fragment granules: [gy*16+ks][slab 8][half 2][lane 64] us8 ----
__global__ void k_pack_x(const float* __restrict__ x, us8* __restrict__ xpk) {
    const int gy = blockIdx.x >> 2, q = blockIdx.x & 3;
    const int t = threadIdx.x;
    us8* dst = xpk + (size_t)gy * 16384;
#pragma unroll
    for (int jj = 0; jj < 16; ++jj) {
        const int o = q * 4096 + jj * 256 + t;
        const int lane = o & 63, half = (o >> 6) & 1, slab = (o >> 7) & 7, ks = o >> 10;
        const int row = gy * 128 + slab * 16 + (lane & 15);
        const int kb = ks * 32 + (lane >> 4) * 8;
        const float4* p = (const float4*)(x + (size_t)row * VEC + kb);
        float4 f0 = p[0], f1 = p[1];
        float ff[8] = {f0.x, f0.y, f0.z, f0.w, f1.x, f1.y, f1.z, f1.w};
        us8 v;
#pragma unroll
        for (int j = 0; j < 8; ++j) v[j] = half ? lo_of(ff[j]) : hi_of(ff[j]);
        dst[o] = v;
    }
}

// ---- main kernel: split-bf16 MFMA distance GEMM + per-row argmin merge ----
// XCD swizzle: gy = (blk&7)*64 + (blk>>6), gx = (blk>>3)&7 -> one XCD owns a
// contiguous gy range and its 8 col-blocks co-reside -> x fetched ~once.
template<bool APK>
__launch_bounds__(256, 2)
__global__ void k_gemm_argmin(const float* __restrict__ x, const us8* __restrict__ xpk,
                              const us8* __restrict__ wpk, const float* __restrict__ w2,
                              u64* __restrict__ keys) {
    __shared__ us8 a_lds[2][1024];   // 16 KB per buf
    __shared__ us8 b_lds[2][1024];

    const int blk = blockIdx.x;
    const int gy = (blk & 7) * 64 + ((blk >> 3) >> 3);
    const int gx = (blk >> 3) & 7;
    const int row0 = gy * BM;
    const int col0 = gx * BN;
    const int t = threadIdx.x;
    const int wv = t >> 6, lane = t & 63;

    // !APK A-staging identities: source s = r*256+t -> slab = r*4+(t>>6), lane_s = t&63
    const int arow_base = (t >> 6) * 16 + (t & 15);
    const int akoff = ((t >> 4) & 3) * 8;
    float4 af[2][2];

    auto aload = [&](int ks) {
#pragma unroll
        for (int r = 0; r < 2; ++r) {
            const float4* p = (const float4*)(x + (size_t)(row0 + arow_base + r * 64) * VEC + ks * BK + akoff);
            af[r][0] = p[0];
            af[r][1] = p[1];
        }
    };
    auto awrite = [&](int buf) {
#pragma unroll
        for (int r = 0; r < 2; ++r) {
            const float* ff = (const float*)&af[r][0];
            us8 h, l;
#pragma unroll
            for (int j = 0; j < 8; ++j) { h[j] = hi_of(ff[j]); l[j] = lo_of(ff[j]); }
            const int c0 = (r * 4 + (t >> 6)) * 128 + (t & 63);
            a_lds[buf][c0] = h;
            a_lds[buf][c0 + 64] = l;
        }
    };
    auto astage_gl = [&](int ks, int buf) {
        const us8* src = xpk + (size_t)(gy * 16 + ks) * 1024;
#pragma unroll
        for (int r = 0; r < 4; ++r)
            gl16(src + r * 256 + t, &a_lds[buf][r * 256 + t]);
    };
    auto bstage = [&](int ks, int buf) {
        const us8* src = wpk + (size_t)(gx * 16 + ks) * 1024;
#pragma unroll
        for (int r = 0; r < 4; ++r)
            gl16(src + r * 256 + t, &b_lds[buf][r * 256 + t]);
    };

    const int wr = wv >> 1, wc = wv & 1;

    f32x4 acc[4][4];
#pragma unroll
    for (int i = 0; i < 4; ++i)
#pragma unroll
        for (int j = 0; j < 4; ++j) acc[i][j] = (f32x4){0.f, 0.f, 0.f, 0.f};

    if (APK) {
        astage_gl(0, 0);
    } else {
        aload(0);
        awrite(0);
    }
    bstage(0, 0);
    __syncthreads();

    for (int ks = 0; ks < NK; ++ks) {
        const int buf = ks & 1;
        const bool next = (ks + 1 < NK);
        if (next) {
            if (APK) astage_gl(ks + 1, buf ^ 1);
            else aload(ks + 1);
            bstage(ks + 1, buf ^ 1);
        }

        bf16x8 ah[4], al[4];
#pragma unroll
        for (int rt = 0; rt < 4; ++rt) {
            const int c0 = (wr * 4 + rt) * 128 + lane;
            ah[rt] = __builtin_bit_cast(bf16x8, a_lds[buf][c0]);
            al[rt] = __builtin_bit_cast(bf16x8, a_lds[buf][c0 + 64]);
        }
#pragma unroll
        for (int ct = 0; ct < 4; ++ct) {
            const int c0 = (wc * 4 + ct) * 128 + lane;
            bf16x8 bh = __builtin_bit_cast(bf16x8, b_lds[buf][c0]);
            bf16x8 bl = __builtin_bit_cast(bf16x8, b_lds[buf][c0 + 64]);
#pragma unroll
            for (int rt = 0; rt < 4; ++rt) {
                acc[rt][ct] = __builtin_amdgcn_mfma_f32_16x16x32_bf16(ah[rt], bh, acc[rt][ct], 0, 0, 0);
                acc[rt][ct] = __builtin_amdgcn_mfma_f32_16x16x32_bf16(ah[rt], bl, acc[rt][ct], 0, 0, 0);
                acc[rt][ct] = __builtin_amdgcn_mfma_f32_16x16x32_bf16(al[rt], bh, acc[rt][ct], 0, 0, 0);
            }
        }
        if (next && !APK) awrite(buf ^ 1);
        __syncthreads();
    }

    float w2c[4];
#pragma unroll
    for (int ct = 0; ct < 4; ++ct)
        w2c[ct] = w2[col0 + wc * 64 + ct * 16 + (lane & 15)];

#pragma unroll
    for (int rt = 0; rt < 4; ++rt) {
#pragma unroll
        for (int reg = 0; reg < 4; ++reg) {
            u64 km = ~0ull;
#pragma unroll
            for (int ct = 0; ct < 4; ++ct) {
                float dist = w2c[ct] - 2.0f * acc[rt][ct][reg];
                uint su = __float_as_uint(dist);
                su = (su & 0x80000000u) ? ~su : (su | 0x80000000u);
                const int col = col0 + wc * 64 + ct * 16 + (lane & 15);
                u64 key = ((u64)su << 32) | (uint)col;
                km = key < km ? key : km;
            }
#pragma unroll
            for (int m = 1; m < 16; m <<= 1) {
                u64 o = __shfl_xor((unsigned long long)km, m);
                km = o < km ? o : km;
            }
            if ((lane & 15) == 0) {
                const int row = row0 + wr * 64 + rt * 16 + (lane >> 4) * 4 + reg;
                atomicMin((unsigned long long*)&keys[row], (unsigned long long)km);
            }
        }
    }
}

// ---- histogram from keys ----
__global__ void k_hist(const u64* __restrict__ keys, int* __restrict__ counts) {
    const int b = blockIdx.x * blockDim.x + threadIdx.x;
    atomicAdd(&counts[(uint)(keys[b] & 0xffffffffull)], 1);
}

// ---- scan of counts -> offsets; EMA cluster sizes -> cs ----
__global__ void k_scan(const int* __restrict__ counts,
                       const float* __restrict__ cluster_size,
                       int* __restrict__ offsets, float* __restrict__ cs) {
    __shared__ int sa[K];
    __shared__ int sb[K];
    __shared__ float sf[K];
    const int t = threadIdx.x;
    const int c = counts[t];

    sa[t] = c;
    __syncthreads();
    int* src = sa;
    int* dst = sb;
    for (int d = 1; d < K; d <<= 1) {
        dst[t] = src[t] + ((t >= d) ? src[t - d] : 0);
        __syncthreads();
        int* tmp = src; src = dst; dst = tmp;
    }
    offsets[t] = src[t] - c;

    float ncs = GAMMA * cluster_size[t] + (1.0f - GAMMA) * ((c == 0) ? 1.0f : (float)c);
    sf[t] = ncs;
    __syncthreads();
    for (int d = K / 2; d > 0; d >>= 1) {
        if (t < d) sf[t] += sf[t + d];
        __syncthreads();
    }
    float n = sf[0];
    cs[t] = (ncs + EPS) / (n + (float)K * EPS) * n;
}

// ---- counting-sort scatter ----
__global__ void k_scatter(const u64* __restrict__ keys, const int* __restrict__ offsets,
                          int* __restrict__ cursor, int* __restrict__ sorted,
                          int* __restrict__ sortedk) {
    const int b = blockIdx.x * blockDim.x + threadIdx.x;
    const int k = (int)(uint)(keys[b] & 0xffffffffull);
    const int pos = atomicAdd(&cursor[k], 1);
    sorted[offsets[k] + pos] = b;
    sortedk[offsets[k] + pos] = k;
}

// ---- balanced segmented reduction: 64 sorted rows per block ----
__launch_bounds__(512)
__global__ void k_segred(const float* __restrict__ x, const int* __restrict__ sorted,
                         const int* __restrict__ sortedk, float* __restrict__ esum) {
    __shared__ int srow[SEG];
    __shared__ int skid[SEG];
    const int b = blockIdx.x;
    const int t = threadIdx.x;
    if (t < SEG) {
        srow[t] = sorted[b * SEG + t];
        skid[t] = sortedk[b * SEG + t];
    }
    __syncthreads();

    float a = 0.f;
    int cur = skid[0];
#pragma unroll 8
    for (int i = 0; i < SEG; ++i) {
        const int k = skid[i];
        if (k != cur) {
            atomicAdd(&esum[(size_t)cur * VEC + t], a);
            a = 0.f;
            cur = k;
        }
        a += x[(size_t)srow[i] * VEC + t];
    }
    atomicAdd(&esum[(size_t)cur * VEC + t], a);
}

// ---- finalize: transpose esum (K,VEC)->(VEC,K), EMA + normalize ----
__launch_bounds__(256)
__global__ void k_finalize(const float* __restrict__ esum, const float* __restrict__ embed_avg,
                           const float* __restrict__ cs, float* __restrict__ out) {
    __shared__ float tile[64][65];
    const int k0 = blockIdx.x * 64;
    const int v0 = blockIdx.y * 64;
    const int c = threadIdx.x & 63;
    const int r0 = threadIdx.x >> 6;
#pragma unroll
    for (int j = 0; j < 16; ++j) {
        const int r = r0 + j * 4;
        tile[r][c] = esum[(size_t)(k0 + r) * VEC + v0 + c];
    }
    __syncthreads();
    const float csk = cs[k0 + c];
#pragma unroll
    for (int j = 0; j < 16; ++j) {
        const int r = r0 + j * 4;
        const size_t o = (size_t)(v0 + r) * K + k0 + c;
        out[o] = (GAMMA * embed_avg[o] + (1.0f - GAMMA) * tile[c][r]) / csk;
    }
}

extern "C" void kernel_launch(void* const* d_in, const int* in_sizes, int n_in,
                              void* d_out, int out_size, void* d_ws, size_t ws_size,
                              hipStream_t stream) {
    const float* x            = (const float*)d_in[0];   // (BATCH, VEC)
    const float* w            = (const float*)d_in[1];   // (VEC, K)
    const float* cluster_size = (const float*)d_in[2];   // (K,)
    const float* embed_avg    = (const float*)d_in[3];   // (VEC, K)
    float* out = (float*)d_out;                          // (VEC, K)

    // ws: keys | w2 | cs | counts | cursor | offsets | sorted | sortedk | esum | wpk | [xpk]
    u64*   keys    = (u64*)d_ws;
    float* w2      = (float*)(keys + BATCH);
    float* cs      = w2 + K;
    int*   counts  = (int*)(cs + K);
    int*   cursor  = counts + K;
    int*   offsets = cursor + K;
    int*   sorted  = offsets + K;
    int*   sortedk = sorted + BATCH;
    float* esum    = (float*)(sortedk + BATCH);          // (K, VEC), 2 MB
    us8*   wpk     = (us8*)(esum + (size_t)K * VEC);     // 2 MB (128 granules x 1024 chunks)
    us8*   xpk     = wpk + (size_t)128 * 1024;           // 128 MB (8192 granules x 1024 chunks)
    const size_t need_apk = (size_t)((char*)(xpk + (size_t)512 * 16 * 1024) - (char*)d_ws);
    const bool apk = (ws_size >= need_apk);

    hipMemsetAsync(keys, 0xFF, (size_t)BATCH * sizeof(u64), stream);
    hipMemsetAsync(counts, 0, 2 * K * sizeof(int), stream);          // counts + cursor
    hipMemsetAsync(esum, 0, (size_t)K * VEC * sizeof(float), stream);

    k_w2<<<K / 16, 256, 0, stream>>>(w, w2);
    k_pack_w<<<128, 256, 0, stream>>>(w, wpk);
    if (apk) {
        k_pack_x<<<2048, 256, 0, stream>>>(x, xpk);
        k_gemm_argmin<true><<<(BATCH / BM) * (K / BN), 256, 0, stream>>>(x, xpk, wpk, w2, keys);
    } else {
        k_gemm_argmin<false><<<(BATCH / BM) * (K / BN), 256, 0, stream>>>(x, xpk, wpk, w2, keys);
    }
    k_hist<<<BATCH / 256, 256, 0, stream>>>(keys, counts);
    k_scan<<<1, K, 0, stream>>>(counts, cluster_size, offsets, cs);
    k_scatter<<<BATCH / 256, 256, 0, stream>>>(keys, offsets, cursor, sorted, sortedk);
    k_segred<<<BATCH / SEG, 512, 0, stream>>>(x, sorted, sortedk, esum);
    k_finalize<<<dim3(K / 64, VEC / 64), 256, 0, stream>>>(esum, embed_avg, cs, out);
}